// Round 19
// baseline (149.824 us; speedup 1.0000x reference)
//
#include <hip/hip_runtime.h>
#include <hip/hip_bf16.h>
#include <hip/hip_fp16.h>
#include <cstddef>

#define N_NODES 50000
#define IN_DIM 256
#define HID_DIM 64
#define OUT_DIM 40
#define N_EDGES 800000
#define NBLK 196            // ceil(N_NODES / 256)
#define GEMM1_BLOCKS 782    // ceil(N_NODES / 64)
#define CNT_BLOCKS 391      // ceil(N_EDGES / 2048), 8 edges/thread
#define FILL_BLOCKS 3125
#define SCALE_BLOCKS 1563   // ceil(N_NODES*64/8 / 256)

typedef _Float16 f16x8 __attribute__((ext_vector_type(8)));
typedef float f32x4 __attribute__((ext_vector_type(4)));

// ---------------------------------------------------------------------------
// K0: zero histogram + build W1^T in fp16 (w1t[c][k] = W1[k][c])
__global__ void k_init(int* __restrict__ cnt, const float* __restrict__ W1,
                       __half* __restrict__ w1t) {
    int i = blockIdx.x * 256 + threadIdx.x;
    if (i < N_NODES) cnt[i] = 0;
    if (i < IN_DIM * HID_DIM) {
        int c = i >> 8, k = i & 255;
        w1t[i] = __float2half(W1[(size_t)k * HID_DIM + c]);
    }
}

// K1: FUSED gemm1 (UNSCALED h1) + degree-count. Independent work:
// blocks [0, GEMM1_BLOCKS) = h1 = x @ W1 via fp16 MFMA (K-split staging);
// blocks [GEMM1_BLOCKS, +CNT_BLOCKS) = count, 8 edges/thread so 8
// atomic-with-return ops pipeline per lane (R18 was latency-bound at 1).
__global__ __launch_bounds__(256) void k_gemm1_count(
        const float* __restrict__ x, const __half* __restrict__ w1t,
        __half* __restrict__ h1,
        const int* __restrict__ dst, int* __restrict__ cnt,
        unsigned short* __restrict__ rank_) {
    __shared__ _Float16 xh[64][136];
    __shared__ _Float16 wt[64][136];
    const int tid = threadIdx.x;
    if (blockIdx.x >= GEMM1_BLOCKS) {            // ---- count path ----
        int base = (blockIdx.x - GEMM1_BLOCKS) * 2048 + tid;
        int d[8];
#pragma unroll
        for (int k = 0; k < 8; ++k) {            // 8 coalesced, independent loads
            int i = base + k * 256;
            d[k] = (i < N_EDGES) ? dst[i] : -1;
        }
#pragma unroll
        for (int k = 0; k < 8; ++k) {            // 8 independent atomics in flight
            int i = base + k * 256;
            if (i < N_EDGES)
                rank_[i] = (unsigned short)atomicAdd(&cnt[d[k]], 1);
        }
        return;
    }
    // ---- gemm1 path (two K=128 phases) ----
    const int row0 = blockIdx.x * 64;
    const int r = tid >> 2, q = tid & 3;
    const int wv = tid >> 6, l = tid & 63;
    const int rowa = wv * 16 + (l & 15);
    const int koff = (l >> 4) * 8;
    const int grow_s = row0 + r;
    f32x4 acc0 = {0.f, 0.f, 0.f, 0.f}, acc1 = acc0, acc2 = acc0, acc3 = acc0;
#pragma unroll
    for (int kh = 0; kh < 2; ++kh) {
        __syncthreads();                         // prev half fully consumed
        {
            const uint4* wsrc = (const uint4*)(w1t + (size_t)r * 256 + kh * 128 + q * 32);
            uint4* wdst = (uint4*)&wt[r][q * 32];
#pragma unroll
            for (int i = 0; i < 4; ++i) wdst[i] = wsrc[i];
            const float4* xsrc = (const float4*)(x + (size_t)grow_s * IN_DIM + kh * 128 + q * 32);
#pragma unroll
            for (int i = 0; i < 4; ++i) {
                float4 f0 = make_float4(0.f, 0.f, 0.f, 0.f), f1 = f0;
                if (grow_s < N_NODES) { f0 = xsrc[2 * i]; f1 = xsrc[2 * i + 1]; }
                f16x8 v;
                v[0] = (_Float16)f0.x; v[1] = (_Float16)f0.y;
                v[2] = (_Float16)f0.z; v[3] = (_Float16)f0.w;
                v[4] = (_Float16)f1.x; v[5] = (_Float16)f1.y;
                v[6] = (_Float16)f1.z; v[7] = (_Float16)f1.w;
                *(f16x8*)&xh[r][q * 32 + i * 8] = v;
            }
        }
        __syncthreads();
#pragma unroll
        for (int ks = 0; ks < 4; ++ks) {
            f16x8 a  = *(const f16x8*)&xh[rowa][ks * 32 + koff];
            f16x8 b0 = *(const f16x8*)&wt[ 0 + (l & 15)][ks * 32 + koff];
            f16x8 b1 = *(const f16x8*)&wt[16 + (l & 15)][ks * 32 + koff];
            f16x8 b2 = *(const f16x8*)&wt[32 + (l & 15)][ks * 32 + koff];
            f16x8 b3 = *(const f16x8*)&wt[48 + (l & 15)][ks * 32 + koff];
            acc0 = __builtin_amdgcn_mfma_f32_16x16x32_f16(a, b0, acc0, 0, 0, 0);
            acc1 = __builtin_amdgcn_mfma_f32_16x16x32_f16(a, b1, acc1, 0, 0, 0);
            acc2 = __builtin_amdgcn_mfma_f32_16x16x32_f16(a, b2, acc2, 0, 0, 0);
            acc3 = __builtin_amdgcn_mfma_f32_16x16x32_f16(a, b3, acc3, 0, 0, 0);
        }
    }
    // C/D: col = lane&15, row = (lane>>4)*4 + reg  [m89-verified]
    const int colc = l & 15;
#pragma unroll
    for (int rr = 0; rr < 4; ++rr) {
        int grow = row0 + wv * 16 + (l >> 4) * 4 + rr;
        if (grow < N_NODES) {
            __half* dst2 = h1 + (size_t)grow * HID_DIM;
            dst2[ 0 + colc] = __float2half(acc0[rr]);
            dst2[16 + colc] = __float2half(acc1[rr]);
            dst2[32 + colc] = __float2half(acc2[rr]);
            dst2[48 + colc] = __float2half(acc3[rr]);
        }
    }
}

// K2a: per-block exclusive scan of cnt -> rowptr (block-local) + block sums
__global__ void k_scan1(const int* __restrict__ cnt, int* __restrict__ excl,
                        int* __restrict__ bsum) {
    __shared__ int wsum[4];
    int i = blockIdx.x * 256 + threadIdx.x;
    int lane = threadIdx.x & 63, w = threadIdx.x >> 6;
    int v = (i < N_NODES) ? cnt[i] : 0;
    int inc = v;
    for (int o = 1; o < 64; o <<= 1) {
        int t = __shfl_up(inc, o);
        if (lane >= o) inc += t;
    }
    if (lane == 63) wsum[w] = inc;
    __syncthreads();
    int off = 0;
    for (int k = 0; k < w; ++k) off += wsum[k];
    if (i < N_NODES) excl[i] = off + inc - v;
    if (threadIdx.x == 255) bsum[blockIdx.x] = off + inc;
}

// K2b: MERGED scan2+scan3: every block redundantly scans the 196 block sums,
// applies its own offset, computes dinv.
__global__ void k_scan23(int* __restrict__ rowptr, const int* __restrict__ bsum,
                         const int* __restrict__ cnt, float* __restrict__ dinv) {
    __shared__ int wsum[4];
    __shared__ int myoff;
    int t = threadIdx.x;
    int lane = t & 63, w = t >> 6;
    int v = (t < NBLK) ? bsum[t] : 0;
    int inc = v;
    for (int o = 1; o < 64; o <<= 1) {
        int u = __shfl_up(inc, o);
        if (lane >= o) inc += u;
    }
    if (lane == 63) wsum[w] = inc;
    __syncthreads();
    int off = 0;
    for (int k = 0; k < w; ++k) off += wsum[k];
    if (t == blockIdx.x) myoff = off + inc - v;
    __syncthreads();
    int i = blockIdx.x * 256 + t;
    if (i < N_NODES) {
        rowptr[i] += myoff;
        dinv[i] = rsqrtf((float)cnt[i] + 1.0f);
    } else if (i == N_NODES) {
        rowptr[i] = N_EDGES;
    }
}

// K3: FUSED fill + g1-scale. Blocks [0, FILL_BLOCKS) = atomic-free CSR fill;
// blocks [FILL_BLOCKS, +SCALE_BLOCKS) = g1[row][*] *= dinv[row] (in place).
__global__ void k_fill_scale(const int* __restrict__ src, const int* __restrict__ dst,
                             const int* __restrict__ rowptr,
                             const unsigned short* __restrict__ rank_,
                             unsigned short* __restrict__ esrc,
                             __half* __restrict__ g1, const float* __restrict__ dinv) {
    if (blockIdx.x < FILL_BLOCKS) {
        int i = blockIdx.x * 256 + threadIdx.x;
        if (i < N_EDGES) {
            int d = dst[i];
            esrc[rowptr[d] + rank_[i]] = (unsigned short)src[i];
        }
        return;
    }
    int idx = (blockIdx.x - FILL_BLOCKS) * 256 + threadIdx.x;   // uint4 index
    if (idx >= N_NODES * HID_DIM / 8) return;
    int row = idx >> 3;
    float dv = dinv[row];
    uint4 v = *(uint4*)&g1[(size_t)idx * 8];
    union { __half2 h2v[4]; uint4 u; } pk;
    const __half2* hv = (const __half2*)&v;
#pragma unroll
    for (int i = 0; i < 4; ++i) {
        float2 f = __half22float2(hv[i]);
        pk.h2v[i] = __floats2half2_rn(f.x * dv, f.y * dv);
    }
    *(uint4*)&g1[(size_t)idx * 8] = pk.u;
}

// K4: gather aggregation DIM=64 (pre-scaled fp16 in), fused bias+ReLU,
// fp16 output. uint4 structure: 8 parities x 8 lanes x 16B.
__global__ __launch_bounds__(256) void k_agg_relu(const int* __restrict__ rowptr,
        const unsigned short* __restrict__ esrc, const float* __restrict__ dinv,
        const uint4* __restrict__ g,        // [N][8] uint4 (=64 half)
        const float* __restrict__ b,
        __half* __restrict__ out) {         // agg1 [N][64] fp16
    int wid  = (int)((blockIdx.x * (size_t)blockDim.x + threadIdx.x) >> 6);
    int lane = threadIdx.x & 63;
    if (wid >= N_NODES) return;
    int p = lane >> 3;        // edge parity 0..7
    int c = lane & 7;         // uint4 channel group (8 halves)
    float a0 = 0.f, a1 = 0.f, a2 = 0.f, a3 = 0.f;
    float a4 = 0.f, a5 = 0.f, a6 = 0.f, a7 = 0.f;
#define ACC_U4(v)  do {                                            \
        float2 f0 = __half22float2(*(const __half2*)&(v).x);       \
        float2 f1 = __half22float2(*(const __half2*)&(v).y);       \
        float2 f2 = __half22float2(*(const __half2*)&(v).z);       \
        float2 f3 = __half22float2(*(const __half2*)&(v).w);       \
        a0 += f0.x; a1 += f0.y; a2 += f1.x; a3 += f1.y;            \
        a4 += f2.x; a5 += f2.y; a6 += f3.x; a7 += f3.y; } while (0)
    if (p == 0) { uint4 v = g[(size_t)wid * 8 + c]; ACC_U4(v); }   // self-loop
    int beg = rowptr[wid], deg = rowptr[wid + 1] - beg;
    for (int base = 0; base < deg; base += 64) {          // uniform
        int nb = deg - base; if (nb > 64) nb = 64;        // uniform
        int idx = (lane < nb) ? (int)esrc[beg + base + lane] : 0;  // coalesced
        for (int eb = 0; eb < nb; eb += 32) {             // uniform bound
            int e0 = eb + p;                              // e0+24 <= 63 always
            int s0 = __shfl(idx, e0);
            int s1 = __shfl(idx, e0 + 8);
            int s2 = __shfl(idx, e0 + 16);
            int s3 = __shfl(idx, e0 + 24);
            if (e0 + 24 < nb) {                           // fast path: all 4
                uint4 v0 = g[(size_t)s0 * 8 + c];
                uint4 v1 = g[(size_t)s1 * 8 + c];
                uint4 v2 = g[(size_t)s2 * 8 + c];
                uint4 v3 = g[(size_t)s3 * 8 + c];
                ACC_U4(v0); ACC_U4(v1); ACC_U4(v2); ACC_U4(v3);
            } else {                                      // tail: per-edge guard
                if (e0      < nb) { uint4 v = g[(size_t)s0 * 8 + c]; ACC_U4(v); }
                if (e0 + 8  < nb) { uint4 v = g[(size_t)s1 * 8 + c]; ACC_U4(v); }
                if (e0 + 16 < nb) { uint4 v = g[(size_t)s2 * 8 + c]; ACC_U4(v); }
            }
        }
    }
#undef ACC_U4
    a0 += __shfl_xor(a0, 8); a0 += __shfl_xor(a0, 16); a0 += __shfl_xor(a0, 32);
    a1 += __shfl_xor(a1, 8); a1 += __shfl_xor(a1, 16); a1 += __shfl_xor(a1, 32);
    a2 += __shfl_xor(a2, 8); a2 += __shfl_xor(a2, 16); a2 += __shfl_xor(a2, 32);
    a3 += __shfl_xor(a3, 8); a3 += __shfl_xor(a3, 16); a3 += __shfl_xor(a3, 32);
    a4 += __shfl_xor(a4, 8); a4 += __shfl_xor(a4, 16); a4 += __shfl_xor(a4, 32);
    a5 += __shfl_xor(a5, 8); a5 += __shfl_xor(a5, 16); a5 += __shfl_xor(a5, 32);
    a6 += __shfl_xor(a6, 8); a6 += __shfl_xor(a6, 16); a6 += __shfl_xor(a6, 32);
    a7 += __shfl_xor(a7, 8); a7 += __shfl_xor(a7, 16); a7 += __shfl_xor(a7, 32);
    if (lane < 8) {
        float dd = dinv[wid];
        float4 b0v = *(const float4*)&b[c * 8 + 0];
        float4 b1v = *(const float4*)&b[c * 8 + 4];
        union { __half2 h2v[4]; uint4 u; } pk;
        pk.h2v[0] = __floats2half2_rn(fmaxf(a0 * dd + b0v.x, 0.f),
                                      fmaxf(a1 * dd + b0v.y, 0.f));
        pk.h2v[1] = __floats2half2_rn(fmaxf(a2 * dd + b0v.z, 0.f),
                                      fmaxf(a3 * dd + b0v.w, 0.f));
        pk.h2v[2] = __floats2half2_rn(fmaxf(a4 * dd + b1v.x, 0.f),
                                      fmaxf(a5 * dd + b1v.y, 0.f));
        pk.h2v[3] = __floats2half2_rn(fmaxf(a6 * dd + b1v.z, 0.f),
                                      fmaxf(a7 * dd + b1v.w, 0.f));
        *(uint4*)&out[(size_t)wid * HID_DIM + c * 8] = pk.u;
    }
}

// K5: g2 = dinv * (a @ W2)  [50000,64]x[64,40]; fp16 in, fp16 out [N][40]
__global__ void k_gemm2(const __half* __restrict__ a, const float* __restrict__ W2,
                        const float* __restrict__ dinv, __half* __restrict__ g2) {
    int idx = blockIdx.x * blockDim.x + threadIdx.x;
    if (idx >= N_NODES * (OUT_DIM / 4)) return;
    int row = idx / (OUT_DIM / 4);
    int cg  = idx - row * (OUT_DIM / 4);
    const uint2* ar = (const uint2*)(a + (size_t)row * HID_DIM);
    float4 acc = make_float4(0.f, 0.f, 0.f, 0.f);
#pragma unroll
    for (int kk = 0; kk < 16; ++kk) {
        uint2 hv = ar[kk];
        float2 f0 = __half22float2(*(const __half2*)&hv.x);
        float2 f1 = __half22float2(*(const __half2*)&hv.y);
        float4 w0 = *(const float4*)&W2[(kk * 4 + 0) * OUT_DIM + cg * 4];
        float4 w1 = *(const float4*)&W2[(kk * 4 + 1) * OUT_DIM + cg * 4];
        float4 w2 = *(const float4*)&W2[(kk * 4 + 2) * OUT_DIM + cg * 4];
        float4 w3 = *(const float4*)&W2[(kk * 4 + 3) * OUT_DIM + cg * 4];
        acc.x += f0.x * w0.x + f0.y * w1.x + f1.x * w2.x + f1.y * w3.x;
        acc.y += f0.x * w0.y + f0.y * w1.y + f1.x * w2.y + f1.y * w3.y;
        acc.z += f0.x * w0.z + f0.y * w1.z + f1.x * w2.z + f1.y * w3.z;
        acc.w += f0.x * w0.w + f0.y * w1.w + f1.x * w2.w + f1.y * w3.w;
    }
    float dv = dinv[row];
    union { __half2 h2v[2]; uint2 u; } pk;
    pk.h2v[0] = __floats2half2_rn(acc.x * dv, acc.y * dv);
    pk.h2v[1] = __floats2half2_rn(acc.z * dv, acc.w * dv);
    *(uint2*)&g2[(size_t)row * OUT_DIM + cg * 4] = pk.u;
}

// K6: layer-2 aggregation (pre-scaled fp16 in), fused bias + log_softmax.
// R10-proven uint2 structure (unpadded [N][40]).
__global__ __launch_bounds__(256) void k_agg_lsm(const int* __restrict__ rowptr,
        const unsigned short* __restrict__ esrc, const float* __restrict__ dinv,
        const uint2* __restrict__ g,        // [N][10] uint2 (=40 half)
        const float* __restrict__ b,
        float* __restrict__ out) {
    int wid  = (int)((blockIdx.x * (size_t)blockDim.x + threadIdx.x) >> 6);
    int lane = threadIdx.x & 63;
    if (wid >= N_NODES) return;
    int p = lane >> 4;
    int c = lane & 15;
    bool act = (c < 10);
    float ax = 0.f, ay = 0.f, az = 0.f, aw = 0.f;
#define ACC_U2(v)  do {                                            \
        float2 f0 = __half22float2(*(const __half2*)&(v).x);       \
        float2 f1 = __half22float2(*(const __half2*)&(v).y);       \
        ax += f0.x; ay += f0.y; az += f1.x; aw += f1.y; } while (0)
    if (p == 0 && act) { uint2 v = g[(size_t)wid * 10 + c]; ACC_U2(v); }
    int beg = rowptr[wid], deg = rowptr[wid + 1] - beg;
    for (int base = 0; base < deg; base += 64) {          // uniform
        int nb = deg - base; if (nb > 64) nb = 64;        // uniform
        int idx = (lane < nb) ? (int)esrc[beg + base + lane] : 0;
        for (int eb = 0; eb < nb; eb += 16) {             // uniform bound
            int e0 = eb + p;
            int s0 = __shfl(idx, e0);
            int s1 = __shfl(idx, e0 + 4);
            int s2 = __shfl(idx, e0 + 8);
            int s3 = __shfl(idx, e0 + 12);
            if (act) {
                if (e0 + 12 < nb) {
                    uint2 v0 = g[(size_t)s0 * 10 + c];
                    uint2 v1 = g[(size_t)s1 * 10 + c];
                    uint2 v2 = g[(size_t)s2 * 10 + c];
                    uint2 v3 = g[(size_t)s3 * 10 + c];
                    ACC_U2(v0); ACC_U2(v1); ACC_U2(v2); ACC_U2(v3);
                } else {
                    if (e0      < nb) { uint2 v = g[(size_t)s0 * 10 + c]; ACC_U2(v); }
                    if (e0 + 4  < nb) { uint2 v = g[(size_t)s1 * 10 + c]; ACC_U2(v); }
                    if (e0 + 8  < nb) { uint2 v = g[(size_t)s2 * 10 + c]; ACC_U2(v); }
                }
            }
        }
    }
#undef ACC_U2
    ax += __shfl_xor(ax, 16); ax += __shfl_xor(ax, 32);
    ay += __shfl_xor(ay, 16); ay += __shfl_xor(ay, 32);
    az += __shfl_xor(az, 16); az += __shfl_xor(az, 32);
    aw += __shfl_xor(aw, 16); aw += __shfl_xor(aw, 32);
    float dd = dinv[wid];
    float vx = -INFINITY, vy = -INFINITY, vz = -INFINITY, vw = -INFINITY;
    if (act) {
        float4 bb = *(const float4*)&b[c * 4];
        vx = ax * dd + bb.x; vy = ay * dd + bb.y;
        vz = az * dd + bb.z; vw = aw * dd + bb.w;
    }
    float m = fmaxf(fmaxf(vx, vy), fmaxf(vz, vw));
    for (int o = 8; o; o >>= 1) m = fmaxf(m, __shfl_xor(m, o));
    float es = act ? (__expf(vx - m) + __expf(vy - m) + __expf(vz - m) + __expf(vw - m)) : 0.f;
    for (int o = 8; o; o >>= 1) es += __shfl_xor(es, o);
    float ls = __logf(es);
    if (lane < 16 && act) {
        float4 o4 = make_float4(vx - m - ls, vy - m - ls, vz - m - ls, vw - m - ls);
        *(float4*)&out[(size_t)wid * OUT_DIM + c * 4] = o4;
    }
}

extern "C" void kernel_launch(void* const* d_in, const int* in_sizes, int n_in,
                              void* d_out, int out_size, void* d_ws, size_t ws_size,
                              hipStream_t stream) {
    const float* x    = (const float*)d_in[0];
    const int*   ei   = (const int*)d_in[1];
    const int*   srcp = ei;             // edge_index[0]
    const int*   dstp = ei + N_EDGES;   // edge_index[1]
    const float* W1   = (const float*)d_in[2];
    const float* b1   = (const float*)d_in[3];
    const float* W2   = (const float*)d_in[4];
    const float* b2   = (const float*)d_in[5];
    float* out = (float*)d_out;

    // workspace layout (~21 MB)
    char* p = (char*)d_ws;
    int*            cnt    = (int*)p;            p += (size_t)N_NODES * 4;
    int*            rowptr = (int*)p;            p += (size_t)(N_NODES + 4) * 4;
    unsigned short* rank_  = (unsigned short*)p; p += (size_t)N_EDGES * 2;
    unsigned short* esrc   = (unsigned short*)p; p += (size_t)N_EDGES * 2;
    int*            bsum   = (int*)p;            p += 256 * 4;
    float*          dinv   = (float*)p;          p += (size_t)N_NODES * 4;
    __half*         w1t    = (__half*)p;         p += (size_t)IN_DIM * HID_DIM * 2;
    __half*         g1     = (__half*)p;         p += (size_t)N_NODES * HID_DIM * 2;
    __half*         agg1   = (__half*)p;         p += (size_t)N_NODES * HID_DIM * 2;
    __half*         g2     = (__half*)p;         p += (size_t)N_NODES * OUT_DIM * 2;

    k_init<<<NBLK, 256, 0, stream>>>(cnt, W1, w1t);

    k_gemm1_count<<<GEMM1_BLOCKS + CNT_BLOCKS, 256, 0, stream>>>(
        x, w1t, g1, dstp, cnt, rank_);

    k_scan1<<<NBLK, 256, 0, stream>>>(cnt, rowptr, bsum);
    k_scan23<<<NBLK, 256, 0, stream>>>(rowptr, bsum, cnt, dinv);

    k_fill_scale<<<FILL_BLOCKS + SCALE_BLOCKS, 256, 0, stream>>>(
        srcp, dstp, rowptr, rank_, esrc, g1, dinv);

    k_agg_relu<<<(N_NODES + 3) / 4, 256, 0, stream>>>(rowptr, esrc, dinv,
                                                      (const uint4*)g1, b1, agg1);

    k_gemm2<<<(N_NODES * (OUT_DIM / 4) + 255) / 256, 256, 0, stream>>>(agg1, W2, dinv, g2);

    k_agg_lsm<<<(N_NODES + 3) / 4, 256, 0, stream>>>(rowptr, esrc, dinv,
                                                     (const uint2*)g2, b2, out);
}

// Round 20
// 140.723 us; speedup vs baseline: 1.0647x; 1.0647x over previous
//
#include <hip/hip_runtime.h>
#include <hip/hip_bf16.h>
#include <hip/hip_fp16.h>
#include <cstddef>

#define N_NODES 50000
#define IN_DIM 256
#define HID_DIM 64
#define OUT_DIM 40
#define N_EDGES 800000
#define NBLK 196            // ceil(N_NODES / 256)
#define GEMM1_BLOCKS 782    // ceil(N_NODES / 64)
#define CNT_BLOCKS 3125     // 1 edge/thread (R18-proven; R19's 8/thread regressed)
#define FILL_BLOCKS 3125
#define SCALE_BLOCKS 1563   // ceil(N_NODES*64/8 / 256)

typedef _Float16 f16x8 __attribute__((ext_vector_type(8)));
typedef float f32x4 __attribute__((ext_vector_type(4)));

// ---------------------------------------------------------------------------
// K0: zero histogram + build W1^T in fp16 (w1t[c][k] = W1[k][c])
__global__ void k_init(int* __restrict__ cnt, const float* __restrict__ W1,
                       __half* __restrict__ w1t) {
    int i = blockIdx.x * 256 + threadIdx.x;
    if (i < N_NODES) cnt[i] = 0;
    if (i < IN_DIM * HID_DIM) {
        int c = i >> 8, k = i & 255;
        w1t[i] = __float2half(W1[(size_t)k * HID_DIM + c]);
    }
}

// K1: FUSED gemm1 (UNSCALED h1) + degree-count.
// gemm1 now stages in K=64 phases -> LDS 18 KB (was 34 KB), so COUNT blocks
// (which inherit the kernel's static LDS) run 8 blocks/CU = 32 waves/CU
// instead of 16 (R18's occupancy cap was the count path's limiter).
__global__ __launch_bounds__(256) void k_gemm1_count(
        const float* __restrict__ x, const __half* __restrict__ w1t,
        __half* __restrict__ h1,
        const int* __restrict__ dst, int* __restrict__ cnt,
        unsigned short* __restrict__ rank_) {
    __shared__ _Float16 xh[64][72];   // 64 cols + 8 pad
    __shared__ _Float16 wt[64][72];
    const int tid = threadIdx.x;
    if (blockIdx.x >= GEMM1_BLOCKS) {            // ---- count path ----
        int i = (blockIdx.x - GEMM1_BLOCKS) * 256 + tid;
        if (i < N_EDGES) rank_[i] = (unsigned short)atomicAdd(&cnt[dst[i]], 1);
        return;
    }
    // ---- gemm1 path (four K=64 phases, 18 KB LDS) ----
    const int row0 = blockIdx.x * 64;
    const int r = tid >> 2, q = tid & 3;         // r: row 0..63, q: 16-half quarter
    const int wv = tid >> 6, l = tid & 63;
    const int rowa = wv * 16 + (l & 15);
    const int koff = (l >> 4) * 8;
    const int grow_s = row0 + r;
    f32x4 acc0 = {0.f, 0.f, 0.f, 0.f}, acc1 = acc0, acc2 = acc0, acc3 = acc0;
#pragma unroll
    for (int kh = 0; kh < 4; ++kh) {
        __syncthreads();                         // prev phase fully consumed
        {
            const uint4* wsrc = (const uint4*)(w1t + (size_t)r * 256 + kh * 64 + q * 16);
            uint4* wdst = (uint4*)&wt[r][q * 16];
            wdst[0] = wsrc[0];
            wdst[1] = wsrc[1];
            const float4* xsrc = (const float4*)(x + (size_t)grow_s * IN_DIM + kh * 64 + q * 16);
#pragma unroll
            for (int i = 0; i < 2; ++i) {
                float4 f0 = make_float4(0.f, 0.f, 0.f, 0.f), f1 = f0;
                if (grow_s < N_NODES) { f0 = xsrc[2 * i]; f1 = xsrc[2 * i + 1]; }
                f16x8 v;
                v[0] = (_Float16)f0.x; v[1] = (_Float16)f0.y;
                v[2] = (_Float16)f0.z; v[3] = (_Float16)f0.w;
                v[4] = (_Float16)f1.x; v[5] = (_Float16)f1.y;
                v[6] = (_Float16)f1.z; v[7] = (_Float16)f1.w;
                *(f16x8*)&xh[r][q * 16 + i * 8] = v;
            }
        }
        __syncthreads();
#pragma unroll
        for (int ks = 0; ks < 2; ++ks) {
            f16x8 a  = *(const f16x8*)&xh[rowa][ks * 32 + koff];
            f16x8 b0 = *(const f16x8*)&wt[ 0 + (l & 15)][ks * 32 + koff];
            f16x8 b1 = *(const f16x8*)&wt[16 + (l & 15)][ks * 32 + koff];
            f16x8 b2 = *(const f16x8*)&wt[32 + (l & 15)][ks * 32 + koff];
            f16x8 b3 = *(const f16x8*)&wt[48 + (l & 15)][ks * 32 + koff];
            acc0 = __builtin_amdgcn_mfma_f32_16x16x32_f16(a, b0, acc0, 0, 0, 0);
            acc1 = __builtin_amdgcn_mfma_f32_16x16x32_f16(a, b1, acc1, 0, 0, 0);
            acc2 = __builtin_amdgcn_mfma_f32_16x16x32_f16(a, b2, acc2, 0, 0, 0);
            acc3 = __builtin_amdgcn_mfma_f32_16x16x32_f16(a, b3, acc3, 0, 0, 0);
        }
    }
    // C/D: col = lane&15, row = (lane>>4)*4 + reg  [m89-verified]
    const int colc = l & 15;
#pragma unroll
    for (int rr = 0; rr < 4; ++rr) {
        int grow = row0 + wv * 16 + (l >> 4) * 4 + rr;
        if (grow < N_NODES) {
            __half* dst2 = h1 + (size_t)grow * HID_DIM;
            dst2[ 0 + colc] = __float2half(acc0[rr]);
            dst2[16 + colc] = __float2half(acc1[rr]);
            dst2[32 + colc] = __float2half(acc2[rr]);
            dst2[48 + colc] = __float2half(acc3[rr]);
        }
    }
}

// K2a: per-block exclusive scan of cnt -> rowptr (block-local) + block sums
__global__ void k_scan1(const int* __restrict__ cnt, int* __restrict__ excl,
                        int* __restrict__ bsum) {
    __shared__ int wsum[4];
    int i = blockIdx.x * 256 + threadIdx.x;
    int lane = threadIdx.x & 63, w = threadIdx.x >> 6;
    int v = (i < N_NODES) ? cnt[i] : 0;
    int inc = v;
    for (int o = 1; o < 64; o <<= 1) {
        int t = __shfl_up(inc, o);
        if (lane >= o) inc += t;
    }
    if (lane == 63) wsum[w] = inc;
    __syncthreads();
    int off = 0;
    for (int k = 0; k < w; ++k) off += wsum[k];
    if (i < N_NODES) excl[i] = off + inc - v;
    if (threadIdx.x == 255) bsum[blockIdx.x] = off + inc;
}

// K2b: MERGED scan2+scan3: every block redundantly scans the 196 block sums,
// applies its own offset, computes dinv.
__global__ void k_scan23(int* __restrict__ rowptr, const int* __restrict__ bsum,
                         const int* __restrict__ cnt, float* __restrict__ dinv) {
    __shared__ int wsum[4];
    __shared__ int myoff;
    int t = threadIdx.x;
    int lane = t & 63, w = t >> 6;
    int v = (t < NBLK) ? bsum[t] : 0;
    int inc = v;
    for (int o = 1; o < 64; o <<= 1) {
        int u = __shfl_up(inc, o);
        if (lane >= o) inc += u;
    }
    if (lane == 63) wsum[w] = inc;
    __syncthreads();
    int off = 0;
    for (int k = 0; k < w; ++k) off += wsum[k];
    if (t == blockIdx.x) myoff = off + inc - v;
    __syncthreads();
    int i = blockIdx.x * 256 + t;
    if (i < N_NODES) {
        rowptr[i] += myoff;
        dinv[i] = rsqrtf((float)cnt[i] + 1.0f);
    } else if (i == N_NODES) {
        rowptr[i] = N_EDGES;
    }
}

// K3: FUSED fill + g1-scale. Blocks [0, FILL_BLOCKS) = atomic-free CSR fill;
// blocks [FILL_BLOCKS, +SCALE_BLOCKS) = g1[row][*] *= dinv[row] (in place).
__global__ void k_fill_scale(const int* __restrict__ src, const int* __restrict__ dst,
                             const int* __restrict__ rowptr,
                             const unsigned short* __restrict__ rank_,
                             unsigned short* __restrict__ esrc,
                             __half* __restrict__ g1, const float* __restrict__ dinv) {
    if (blockIdx.x < FILL_BLOCKS) {
        int i = blockIdx.x * 256 + threadIdx.x;
        if (i < N_EDGES) {
            int d = dst[i];
            esrc[rowptr[d] + rank_[i]] = (unsigned short)src[i];
        }
        return;
    }
    int idx = (blockIdx.x - FILL_BLOCKS) * 256 + threadIdx.x;   // uint4 index
    if (idx >= N_NODES * HID_DIM / 8) return;
    int row = idx >> 3;
    float dv = dinv[row];
    uint4 v = *(uint4*)&g1[(size_t)idx * 8];
    union { __half2 h2v[4]; uint4 u; } pk;
    const __half2* hv = (const __half2*)&v;
#pragma unroll
    for (int i = 0; i < 4; ++i) {
        float2 f = __half22float2(hv[i]);
        pk.h2v[i] = __floats2half2_rn(f.x * dv, f.y * dv);
    }
    *(uint4*)&g1[(size_t)idx * 8] = pk.u;
}

// K4: gather aggregation DIM=64 (pre-scaled fp16 in), fused bias+ReLU,
// fp16 output. uint4 structure: 8 parities x 8 lanes x 16B.
__global__ __launch_bounds__(256) void k_agg_relu(const int* __restrict__ rowptr,
        const unsigned short* __restrict__ esrc, const float* __restrict__ dinv,
        const uint4* __restrict__ g,        // [N][8] uint4 (=64 half)
        const float* __restrict__ b,
        __half* __restrict__ out) {         // agg1 [N][64] fp16
    int wid  = (int)((blockIdx.x * (size_t)blockDim.x + threadIdx.x) >> 6);
    int lane = threadIdx.x & 63;
    if (wid >= N_NODES) return;
    int p = lane >> 3;        // edge parity 0..7
    int c = lane & 7;         // uint4 channel group (8 halves)
    float a0 = 0.f, a1 = 0.f, a2 = 0.f, a3 = 0.f;
    float a4 = 0.f, a5 = 0.f, a6 = 0.f, a7 = 0.f;
#define ACC_U4(v)  do {                                            \
        float2 f0 = __half22float2(*(const __half2*)&(v).x);       \
        float2 f1 = __half22float2(*(const __half2*)&(v).y);       \
        float2 f2 = __half22float2(*(const __half2*)&(v).z);       \
        float2 f3 = __half22float2(*(const __half2*)&(v).w);       \
        a0 += f0.x; a1 += f0.y; a2 += f1.x; a3 += f1.y;            \
        a4 += f2.x; a5 += f2.y; a6 += f3.x; a7 += f3.y; } while (0)
    if (p == 0) { uint4 v = g[(size_t)wid * 8 + c]; ACC_U4(v); }   // self-loop
    int beg = rowptr[wid], deg = rowptr[wid + 1] - beg;
    for (int base = 0; base < deg; base += 64) {          // uniform
        int nb = deg - base; if (nb > 64) nb = 64;        // uniform
        int idx = (lane < nb) ? (int)esrc[beg + base + lane] : 0;  // coalesced
        for (int eb = 0; eb < nb; eb += 32) {             // uniform bound
            int e0 = eb + p;                              // e0+24 <= 63 always
            int s0 = __shfl(idx, e0);
            int s1 = __shfl(idx, e0 + 8);
            int s2 = __shfl(idx, e0 + 16);
            int s3 = __shfl(idx, e0 + 24);
            if (e0 + 24 < nb) {                           // fast path: all 4
                uint4 v0 = g[(size_t)s0 * 8 + c];
                uint4 v1 = g[(size_t)s1 * 8 + c];
                uint4 v2 = g[(size_t)s2 * 8 + c];
                uint4 v3 = g[(size_t)s3 * 8 + c];
                ACC_U4(v0); ACC_U4(v1); ACC_U4(v2); ACC_U4(v3);
            } else {                                      // tail: per-edge guard
                if (e0      < nb) { uint4 v = g[(size_t)s0 * 8 + c]; ACC_U4(v); }
                if (e0 + 8  < nb) { uint4 v = g[(size_t)s1 * 8 + c]; ACC_U4(v); }
                if (e0 + 16 < nb) { uint4 v = g[(size_t)s2 * 8 + c]; ACC_U4(v); }
            }
        }
    }
#undef ACC_U4
    a0 += __shfl_xor(a0, 8); a0 += __shfl_xor(a0, 16); a0 += __shfl_xor(a0, 32);
    a1 += __shfl_xor(a1, 8); a1 += __shfl_xor(a1, 16); a1 += __shfl_xor(a1, 32);
    a2 += __shfl_xor(a2, 8); a2 += __shfl_xor(a2, 16); a2 += __shfl_xor(a2, 32);
    a3 += __shfl_xor(a3, 8); a3 += __shfl_xor(a3, 16); a3 += __shfl_xor(a3, 32);
    a4 += __shfl_xor(a4, 8); a4 += __shfl_xor(a4, 16); a4 += __shfl_xor(a4, 32);
    a5 += __shfl_xor(a5, 8); a5 += __shfl_xor(a5, 16); a5 += __shfl_xor(a5, 32);
    a6 += __shfl_xor(a6, 8); a6 += __shfl_xor(a6, 16); a6 += __shfl_xor(a6, 32);
    a7 += __shfl_xor(a7, 8); a7 += __shfl_xor(a7, 16); a7 += __shfl_xor(a7, 32);
    if (lane < 8) {
        float dd = dinv[wid];
        float4 b0v = *(const float4*)&b[c * 8 + 0];
        float4 b1v = *(const float4*)&b[c * 8 + 4];
        union { __half2 h2v[4]; uint4 u; } pk;
        pk.h2v[0] = __floats2half2_rn(fmaxf(a0 * dd + b0v.x, 0.f),
                                      fmaxf(a1 * dd + b0v.y, 0.f));
        pk.h2v[1] = __floats2half2_rn(fmaxf(a2 * dd + b0v.z, 0.f),
                                      fmaxf(a3 * dd + b0v.w, 0.f));
        pk.h2v[2] = __floats2half2_rn(fmaxf(a4 * dd + b1v.x, 0.f),
                                      fmaxf(a5 * dd + b1v.y, 0.f));
        pk.h2v[3] = __floats2half2_rn(fmaxf(a6 * dd + b1v.z, 0.f),
                                      fmaxf(a7 * dd + b1v.w, 0.f));
        *(uint4*)&out[(size_t)wid * HID_DIM + c * 8] = pk.u;
    }
}

// K5: g2 = dinv * (a @ W2)  [50000,64]x[64,40]; fp16 in, fp16 out [N][40]
__global__ void k_gemm2(const __half* __restrict__ a, const float* __restrict__ W2,
                        const float* __restrict__ dinv, __half* __restrict__ g2) {
    int idx = blockIdx.x * blockDim.x + threadIdx.x;
    if (idx >= N_NODES * (OUT_DIM / 4)) return;
    int row = idx / (OUT_DIM / 4);
    int cg  = idx - row * (OUT_DIM / 4);
    const uint2* ar = (const uint2*)(a + (size_t)row * HID_DIM);
    float4 acc = make_float4(0.f, 0.f, 0.f, 0.f);
#pragma unroll
    for (int kk = 0; kk < 16; ++kk) {
        uint2 hv = ar[kk];
        float2 f0 = __half22float2(*(const __half2*)&hv.x);
        float2 f1 = __half22float2(*(const __half2*)&hv.y);
        float4 w0 = *(const float4*)&W2[(kk * 4 + 0) * OUT_DIM + cg * 4];
        float4 w1 = *(const float4*)&W2[(kk * 4 + 1) * OUT_DIM + cg * 4];
        float4 w2 = *(const float4*)&W2[(kk * 4 + 2) * OUT_DIM + cg * 4];
        float4 w3 = *(const float4*)&W2[(kk * 4 + 3) * OUT_DIM + cg * 4];
        acc.x += f0.x * w0.x + f0.y * w1.x + f1.x * w2.x + f1.y * w3.x;
        acc.y += f0.x * w0.y + f0.y * w1.y + f1.x * w2.y + f1.y * w3.y;
        acc.z += f0.x * w0.z + f0.y * w1.z + f1.x * w2.z + f1.y * w3.z;
        acc.w += f0.x * w0.w + f0.y * w1.w + f1.x * w2.w + f1.y * w3.w;
    }
    float dv = dinv[row];
    union { __half2 h2v[2]; uint2 u; } pk;
    pk.h2v[0] = __floats2half2_rn(acc.x * dv, acc.y * dv);
    pk.h2v[1] = __floats2half2_rn(acc.z * dv, acc.w * dv);
    *(uint2*)&g2[(size_t)row * OUT_DIM + cg * 4] = pk.u;
}

// K6: layer-2 aggregation (pre-scaled fp16 in), fused bias + log_softmax.
// R10-proven uint2 structure (unpadded [N][40]).
__global__ __launch_bounds__(256) void k_agg_lsm(const int* __restrict__ rowptr,
        const unsigned short* __restrict__ esrc, const float* __restrict__ dinv,
        const uint2* __restrict__ g,        // [N][10] uint2 (=40 half)
        const float* __restrict__ b,
        float* __restrict__ out) {
    int wid  = (int)((blockIdx.x * (size_t)blockDim.x + threadIdx.x) >> 6);
    int lane = threadIdx.x & 63;
    if (wid >= N_NODES) return;
    int p = lane >> 4;
    int c = lane & 15;
    bool act = (c < 10);
    float ax = 0.f, ay = 0.f, az = 0.f, aw = 0.f;
#define ACC_U2(v)  do {                                            \
        float2 f0 = __half22float2(*(const __half2*)&(v).x);       \
        float2 f1 = __half22float2(*(const __half2*)&(v).y);       \
        ax += f0.x; ay += f0.y; az += f1.x; aw += f1.y; } while (0)
    if (p == 0 && act) { uint2 v = g[(size_t)wid * 10 + c]; ACC_U2(v); }
    int beg = rowptr[wid], deg = rowptr[wid + 1] - beg;
    for (int base = 0; base < deg; base += 64) {          // uniform
        int nb = deg - base; if (nb > 64) nb = 64;        // uniform
        int idx = (lane < nb) ? (int)esrc[beg + base + lane] : 0;
        for (int eb = 0; eb < nb; eb += 16) {             // uniform bound
            int e0 = eb + p;
            int s0 = __shfl(idx, e0);
            int s1 = __shfl(idx, e0 + 4);
            int s2 = __shfl(idx, e0 + 8);
            int s3 = __shfl(idx, e0 + 12);
            if (act) {
                if (e0 + 12 < nb) {
                    uint2 v0 = g[(size_t)s0 * 10 + c];
                    uint2 v1 = g[(size_t)s1 * 10 + c];
                    uint2 v2 = g[(size_t)s2 * 10 + c];
                    uint2 v3 = g[(size_t)s3 * 10 + c];
                    ACC_U2(v0); ACC_U2(v1); ACC_U2(v2); ACC_U2(v3);
                } else {
                    if (e0      < nb) { uint2 v = g[(size_t)s0 * 10 + c]; ACC_U2(v); }
                    if (e0 + 4  < nb) { uint2 v = g[(size_t)s1 * 10 + c]; ACC_U2(v); }
                    if (e0 + 8  < nb) { uint2 v = g[(size_t)s2 * 10 + c]; ACC_U2(v); }
                }
            }
        }
    }
#undef ACC_U2
    ax += __shfl_xor(ax, 16); ax += __shfl_xor(ax, 32);
    ay += __shfl_xor(ay, 16); ay += __shfl_xor(ay, 32);
    az += __shfl_xor(az, 16); az += __shfl_xor(az, 32);
    aw += __shfl_xor(aw, 16); aw += __shfl_xor(aw, 32);
    float dd = dinv[wid];
    float vx = -INFINITY, vy = -INFINITY, vz = -INFINITY, vw = -INFINITY;
    if (act) {
        float4 bb = *(const float4*)&b[c * 4];
        vx = ax * dd + bb.x; vy = ay * dd + bb.y;
        vz = az * dd + bb.z; vw = aw * dd + bb.w;
    }
    float m = fmaxf(fmaxf(vx, vy), fmaxf(vz, vw));
    for (int o = 8; o; o >>= 1) m = fmaxf(m, __shfl_xor(m, o));
    float es = act ? (__expf(vx - m) + __expf(vy - m) + __expf(vz - m) + __expf(vw - m)) : 0.f;
    for (int o = 8; o; o >>= 1) es += __shfl_xor(es, o);
    float ls = __logf(es);
    if (lane < 16 && act) {
        float4 o4 = make_float4(vx - m - ls, vy - m - ls, vz - m - ls, vw - m - ls);
        *(float4*)&out[(size_t)wid * OUT_DIM + c * 4] = o4;
    }
}

extern "C" void kernel_launch(void* const* d_in, const int* in_sizes, int n_in,
                              void* d_out, int out_size, void* d_ws, size_t ws_size,
                              hipStream_t stream) {
    const float* x    = (const float*)d_in[0];
    const int*   ei   = (const int*)d_in[1];
    const int*   srcp = ei;             // edge_index[0]
    const int*   dstp = ei + N_EDGES;   // edge_index[1]
    const float* W1   = (const float*)d_in[2];
    const float* b1   = (const float*)d_in[3];
    const float* W2   = (const float*)d_in[4];
    const float* b2   = (const float*)d_in[5];
    float* out = (float*)d_out;

    // workspace layout (~21 MB)
    char* p = (char*)d_ws;
    int*            cnt    = (int*)p;            p += (size_t)N_NODES * 4;
    int*            rowptr = (int*)p;            p += (size_t)(N_NODES + 4) * 4;
    unsigned short* rank_  = (unsigned short*)p; p += (size_t)N_EDGES * 2;
    unsigned short* esrc   = (unsigned short*)p; p += (size_t)N_EDGES * 2;
    int*            bsum   = (int*)p;            p += 256 * 4;
    float*          dinv   = (float*)p;          p += (size_t)N_NODES * 4;
    __half*         w1t    = (__half*)p;         p += (size_t)IN_DIM * HID_DIM * 2;
    __half*         g1     = (__half*)p;         p += (size_t)N_NODES * HID_DIM * 2;
    __half*         agg1   = (__half*)p;         p += (size_t)N_NODES * HID_DIM * 2;
    __half*         g2     = (__half*)p;         p += (size_t)N_NODES * OUT_DIM * 2;

    k_init<<<NBLK, 256, 0, stream>>>(cnt, W1, w1t);

    k_gemm1_count<<<GEMM1_BLOCKS + CNT_BLOCKS, 256, 0, stream>>>(
        x, w1t, g1, dstp, cnt, rank_);

    k_scan1<<<NBLK, 256, 0, stream>>>(cnt, rowptr, bsum);
    k_scan23<<<NBLK, 256, 0, stream>>>(rowptr, bsum, cnt, dinv);

    k_fill_scale<<<FILL_BLOCKS + SCALE_BLOCKS, 256, 0, stream>>>(
        srcp, dstp, rowptr, rank_, esrc, g1, dinv);

    k_agg_relu<<<(N_NODES + 3) / 4, 256, 0, stream>>>(rowptr, esrc, dinv,
                                                      (const uint4*)g1, b1, agg1);

    k_gemm2<<<(N_NODES * (OUT_DIM / 4) + 255) / 256, 256, 0, stream>>>(agg1, W2, dinv, g2);

    k_agg_lsm<<<(N_NODES + 3) / 4, 256, 0, stream>>>(rowptr, esrc, dinv,
                                                     (const uint2*)g2, b2, out);
}

// Round 21
// 137.805 us; speedup vs baseline: 1.0872x; 1.0212x over previous
//
#include <hip/hip_runtime.h>
#include <hip/hip_bf16.h>
#include <hip/hip_fp16.h>
#include <cstddef>

#define N_NODES 50000
#define IN_DIM 256
#define HID_DIM 64
#define OUT_DIM 40
#define N_EDGES 800000
#define NBLK 196            // ceil(N_NODES / 256)
#define GEMM1_BLOCKS 782    // ceil(N_NODES / 64)
#define CNT_BLOCKS 3125     // 1 edge/thread
#define FILL_BLOCKS 3125
#define SCALE_BLOCKS 1563   // ceil(N_NODES*64/8 / 256)
#define CNT_STRIDE 8        // 32 B per node: 4 nodes per 128 B L2 line (was 32)
#define INIT_BLOCKS 1563    // ceil(N_NODES*CNT_STRIDE / 256)

typedef _Float16 f16x8 __attribute__((ext_vector_type(8)));
typedef float f32x4 __attribute__((ext_vector_type(4)));

// ---------------------------------------------------------------------------
// K0: zero padded histogram + build W1^T in fp16 (w1t[c][k] = W1[k][c])
__global__ void k_init(int* __restrict__ cnt, const float* __restrict__ W1,
                       __half* __restrict__ w1t) {
    int i = blockIdx.x * 256 + threadIdx.x;
    if (i < N_NODES * CNT_STRIDE) cnt[i] = 0;
    if (i < IN_DIM * HID_DIM) {
        int c = i >> 8, k = i & 255;
        w1t[i] = __float2half(W1[(size_t)k * HID_DIM + c]);
    }
}

// K1: FUSED gemm1 (UNSCALED h1) + degree-count.
// Count atomics hit cnt[d*CNT_STRIDE] -- 32 B/node spreads the 128 B
// L2-line RMW serialization 8x (R20 hypothesis test).
__global__ __launch_bounds__(256) void k_gemm1_count(
        const float* __restrict__ x, const __half* __restrict__ w1t,
        __half* __restrict__ h1,
        const int* __restrict__ dst, int* __restrict__ cnt,
        unsigned short* __restrict__ rank_) {
    __shared__ _Float16 xh[64][72];   // 18 KB total (R20-proven occupancy)
    __shared__ _Float16 wt[64][72];
    const int tid = threadIdx.x;
    if (blockIdx.x >= GEMM1_BLOCKS) {            // ---- count path ----
        int i = (blockIdx.x - GEMM1_BLOCKS) * 256 + tid;
        if (i < N_EDGES)
            rank_[i] = (unsigned short)atomicAdd(&cnt[dst[i] * CNT_STRIDE], 1);
        return;
    }
    // ---- gemm1 path (four K=64 phases, 18 KB LDS) ----
    const int row0 = blockIdx.x * 64;
    const int r = tid >> 2, q = tid & 3;
    const int wv = tid >> 6, l = tid & 63;
    const int rowa = wv * 16 + (l & 15);
    const int koff = (l >> 4) * 8;
    const int grow_s = row0 + r;
    f32x4 acc0 = {0.f, 0.f, 0.f, 0.f}, acc1 = acc0, acc2 = acc0, acc3 = acc0;
#pragma unroll
    for (int kh = 0; kh < 4; ++kh) {
        __syncthreads();                         // prev phase fully consumed
        {
            const uint4* wsrc = (const uint4*)(w1t + (size_t)r * 256 + kh * 64 + q * 16);
            uint4* wdst = (uint4*)&wt[r][q * 16];
            wdst[0] = wsrc[0];
            wdst[1] = wsrc[1];
            const float4* xsrc = (const float4*)(x + (size_t)grow_s * IN_DIM + kh * 64 + q * 16);
#pragma unroll
            for (int i = 0; i < 2; ++i) {
                float4 f0 = make_float4(0.f, 0.f, 0.f, 0.f), f1 = f0;
                if (grow_s < N_NODES) { f0 = xsrc[2 * i]; f1 = xsrc[2 * i + 1]; }
                f16x8 v;
                v[0] = (_Float16)f0.x; v[1] = (_Float16)f0.y;
                v[2] = (_Float16)f0.z; v[3] = (_Float16)f0.w;
                v[4] = (_Float16)f1.x; v[5] = (_Float16)f1.y;
                v[6] = (_Float16)f1.z; v[7] = (_Float16)f1.w;
                *(f16x8*)&xh[r][q * 16 + i * 8] = v;
            }
        }
        __syncthreads();
#pragma unroll
        for (int ks = 0; ks < 2; ++ks) {
            f16x8 a  = *(const f16x8*)&xh[rowa][ks * 32 + koff];
            f16x8 b0 = *(const f16x8*)&wt[ 0 + (l & 15)][ks * 32 + koff];
            f16x8 b1 = *(const f16x8*)&wt[16 + (l & 15)][ks * 32 + koff];
            f16x8 b2 = *(const f16x8*)&wt[32 + (l & 15)][ks * 32 + koff];
            f16x8 b3 = *(const f16x8*)&wt[48 + (l & 15)][ks * 32 + koff];
            acc0 = __builtin_amdgcn_mfma_f32_16x16x32_f16(a, b0, acc0, 0, 0, 0);
            acc1 = __builtin_amdgcn_mfma_f32_16x16x32_f16(a, b1, acc1, 0, 0, 0);
            acc2 = __builtin_amdgcn_mfma_f32_16x16x32_f16(a, b2, acc2, 0, 0, 0);
            acc3 = __builtin_amdgcn_mfma_f32_16x16x32_f16(a, b3, acc3, 0, 0, 0);
        }
    }
    // C/D: col = lane&15, row = (lane>>4)*4 + reg  [m89-verified]
    const int colc = l & 15;
#pragma unroll
    for (int rr = 0; rr < 4; ++rr) {
        int grow = row0 + wv * 16 + (l >> 4) * 4 + rr;
        if (grow < N_NODES) {
            __half* dst2 = h1 + (size_t)grow * HID_DIM;
            dst2[ 0 + colc] = __float2half(acc0[rr]);
            dst2[16 + colc] = __float2half(acc1[rr]);
            dst2[32 + colc] = __float2half(acc2[rr]);
            dst2[48 + colc] = __float2half(acc3[rr]);
        }
    }
}

// K2a: per-block exclusive scan of cnt (stride-8) -> rowptr + block sums
__global__ void k_scan1(const int* __restrict__ cnt, int* __restrict__ excl,
                        int* __restrict__ bsum) {
    __shared__ int wsum[4];
    int i = blockIdx.x * 256 + threadIdx.x;
    int lane = threadIdx.x & 63, w = threadIdx.x >> 6;
    int v = (i < N_NODES) ? cnt[i * CNT_STRIDE] : 0;
    int inc = v;
    for (int o = 1; o < 64; o <<= 1) {
        int t = __shfl_up(inc, o);
        if (lane >= o) inc += t;
    }
    if (lane == 63) wsum[w] = inc;
    __syncthreads();
    int off = 0;
    for (int k = 0; k < w; ++k) off += wsum[k];
    if (i < N_NODES) excl[i] = off + inc - v;
    if (threadIdx.x == 255) bsum[blockIdx.x] = off + inc;
}

// K2b: MERGED scan2+scan3: every block redundantly scans the 196 block sums,
// applies its own offset, computes dinv (cnt stride-8).
__global__ void k_scan23(int* __restrict__ rowptr, const int* __restrict__ bsum,
                         const int* __restrict__ cnt, float* __restrict__ dinv) {
    __shared__ int wsum[4];
    __shared__ int myoff;
    int t = threadIdx.x;
    int lane = t & 63, w = t >> 6;
    int v = (t < NBLK) ? bsum[t] : 0;
    int inc = v;
    for (int o = 1; o < 64; o <<= 1) {
        int u = __shfl_up(inc, o);
        if (lane >= o) inc += u;
    }
    if (lane == 63) wsum[w] = inc;
    __syncthreads();
    int off = 0;
    for (int k = 0; k < w; ++k) off += wsum[k];
    if (t == blockIdx.x) myoff = off + inc - v;
    __syncthreads();
    int i = blockIdx.x * 256 + t;
    if (i < N_NODES) {
        rowptr[i] += myoff;
        dinv[i] = rsqrtf((float)cnt[i * CNT_STRIDE] + 1.0f);
    } else if (i == N_NODES) {
        rowptr[i] = N_EDGES;
    }
}

// K3: FUSED fill + g1-scale. Blocks [0, FILL_BLOCKS) = atomic-free CSR fill;
// blocks [FILL_BLOCKS, +SCALE_BLOCKS) = g1[row][*] *= dinv[row] (in place).
__global__ void k_fill_scale(const int* __restrict__ src, const int* __restrict__ dst,
                             const int* __restrict__ rowptr,
                             const unsigned short* __restrict__ rank_,
                             unsigned short* __restrict__ esrc,
                             __half* __restrict__ g1, const float* __restrict__ dinv) {
    if (blockIdx.x < FILL_BLOCKS) {
        int i = blockIdx.x * 256 + threadIdx.x;
        if (i < N_EDGES) {
            int d = dst[i];
            esrc[rowptr[d] + rank_[i]] = (unsigned short)src[i];
        }
        return;
    }
    int idx = (blockIdx.x - FILL_BLOCKS) * 256 + threadIdx.x;   // uint4 index
    if (idx >= N_NODES * HID_DIM / 8) return;
    int row = idx >> 3;
    float dv = dinv[row];
    uint4 v = *(uint4*)&g1[(size_t)idx * 8];
    union { __half2 h2v[4]; uint4 u; } pk;
    const __half2* hv = (const __half2*)&v;
#pragma unroll
    for (int i = 0; i < 4; ++i) {
        float2 f = __half22float2(hv[i]);
        pk.h2v[i] = __floats2half2_rn(f.x * dv, f.y * dv);
    }
    *(uint4*)&g1[(size_t)idx * 8] = pk.u;
}

// K4: gather aggregation DIM=64 (pre-scaled fp16 in), fused bias+ReLU,
// fp16 output. uint4 structure: 8 parities x 8 lanes x 16B.
__global__ __launch_bounds__(256) void k_agg_relu(const int* __restrict__ rowptr,
        const unsigned short* __restrict__ esrc, const float* __restrict__ dinv,
        const uint4* __restrict__ g,        // [N][8] uint4 (=64 half)
        const float* __restrict__ b,
        __half* __restrict__ out) {         // agg1 [N][64] fp16
    int wid  = (int)((blockIdx.x * (size_t)blockDim.x + threadIdx.x) >> 6);
    int lane = threadIdx.x & 63;
    if (wid >= N_NODES) return;
    int p = lane >> 3;        // edge parity 0..7
    int c = lane & 7;         // uint4 channel group (8 halves)
    float a0 = 0.f, a1 = 0.f, a2 = 0.f, a3 = 0.f;
    float a4 = 0.f, a5 = 0.f, a6 = 0.f, a7 = 0.f;
#define ACC_U4(v)  do {                                            \
        float2 f0 = __half22float2(*(const __half2*)&(v).x);       \
        float2 f1 = __half22float2(*(const __half2*)&(v).y);       \
        float2 f2 = __half22float2(*(const __half2*)&(v).z);       \
        float2 f3 = __half22float2(*(const __half2*)&(v).w);       \
        a0 += f0.x; a1 += f0.y; a2 += f1.x; a3 += f1.y;            \
        a4 += f2.x; a5 += f2.y; a6 += f3.x; a7 += f3.y; } while (0)
    if (p == 0) { uint4 v = g[(size_t)wid * 8 + c]; ACC_U4(v); }   // self-loop
    int beg = rowptr[wid], deg = rowptr[wid + 1] - beg;
    for (int base = 0; base < deg; base += 64) {          // uniform
        int nb = deg - base; if (nb > 64) nb = 64;        // uniform
        int idx = (lane < nb) ? (int)esrc[beg + base + lane] : 0;  // coalesced
        for (int eb = 0; eb < nb; eb += 32) {             // uniform bound
            int e0 = eb + p;                              // e0+24 <= 63 always
            int s0 = __shfl(idx, e0);
            int s1 = __shfl(idx, e0 + 8);
            int s2 = __shfl(idx, e0 + 16);
            int s3 = __shfl(idx, e0 + 24);
            if (e0 + 24 < nb) {                           // fast path: all 4
                uint4 v0 = g[(size_t)s0 * 8 + c];
                uint4 v1 = g[(size_t)s1 * 8 + c];
                uint4 v2 = g[(size_t)s2 * 8 + c];
                uint4 v3 = g[(size_t)s3 * 8 + c];
                ACC_U4(v0); ACC_U4(v1); ACC_U4(v2); ACC_U4(v3);
            } else {                                      // tail: per-edge guard
                if (e0      < nb) { uint4 v = g[(size_t)s0 * 8 + c]; ACC_U4(v); }
                if (e0 + 8  < nb) { uint4 v = g[(size_t)s1 * 8 + c]; ACC_U4(v); }
                if (e0 + 16 < nb) { uint4 v = g[(size_t)s2 * 8 + c]; ACC_U4(v); }
            }
        }
    }
#undef ACC_U4
    a0 += __shfl_xor(a0, 8); a0 += __shfl_xor(a0, 16); a0 += __shfl_xor(a0, 32);
    a1 += __shfl_xor(a1, 8); a1 += __shfl_xor(a1, 16); a1 += __shfl_xor(a1, 32);
    a2 += __shfl_xor(a2, 8); a2 += __shfl_xor(a2, 16); a2 += __shfl_xor(a2, 32);
    a3 += __shfl_xor(a3, 8); a3 += __shfl_xor(a3, 16); a3 += __shfl_xor(a3, 32);
    a4 += __shfl_xor(a4, 8); a4 += __shfl_xor(a4, 16); a4 += __shfl_xor(a4, 32);
    a5 += __shfl_xor(a5, 8); a5 += __shfl_xor(a5, 16); a5 += __shfl_xor(a5, 32);
    a6 += __shfl_xor(a6, 8); a6 += __shfl_xor(a6, 16); a6 += __shfl_xor(a6, 32);
    a7 += __shfl_xor(a7, 8); a7 += __shfl_xor(a7, 16); a7 += __shfl_xor(a7, 32);
    if (lane < 8) {
        float dd = dinv[wid];
        float4 b0v = *(const float4*)&b[c * 8 + 0];
        float4 b1v = *(const float4*)&b[c * 8 + 4];
        union { __half2 h2v[4]; uint4 u; } pk;
        pk.h2v[0] = __floats2half2_rn(fmaxf(a0 * dd + b0v.x, 0.f),
                                      fmaxf(a1 * dd + b0v.y, 0.f));
        pk.h2v[1] = __floats2half2_rn(fmaxf(a2 * dd + b0v.z, 0.f),
                                      fmaxf(a3 * dd + b0v.w, 0.f));
        pk.h2v[2] = __floats2half2_rn(fmaxf(a4 * dd + b1v.x, 0.f),
                                      fmaxf(a5 * dd + b1v.y, 0.f));
        pk.h2v[3] = __floats2half2_rn(fmaxf(a6 * dd + b1v.z, 0.f),
                                      fmaxf(a7 * dd + b1v.w, 0.f));
        *(uint4*)&out[(size_t)wid * HID_DIM + c * 8] = pk.u;
    }
}

// K5: g2 = dinv * (a @ W2)  [50000,64]x[64,40]; fp16 in, fp16 out [N][40]
__global__ void k_gemm2(const __half* __restrict__ a, const float* __restrict__ W2,
                        const float* __restrict__ dinv, __half* __restrict__ g2) {
    int idx = blockIdx.x * blockDim.x + threadIdx.x;
    if (idx >= N_NODES * (OUT_DIM / 4)) return;
    int row = idx / (OUT_DIM / 4);
    int cg  = idx - row * (OUT_DIM / 4);
    const uint2* ar = (const uint2*)(a + (size_t)row * HID_DIM);
    float4 acc = make_float4(0.f, 0.f, 0.f, 0.f);
#pragma unroll
    for (int kk = 0; kk < 16; ++kk) {
        uint2 hv = ar[kk];
        float2 f0 = __half22float2(*(const __half2*)&hv.x);
        float2 f1 = __half22float2(*(const __half2*)&hv.y);
        float4 w0 = *(const float4*)&W2[(kk * 4 + 0) * OUT_DIM + cg * 4];
        float4 w1 = *(const float4*)&W2[(kk * 4 + 1) * OUT_DIM + cg * 4];
        float4 w2 = *(const float4*)&W2[(kk * 4 + 2) * OUT_DIM + cg * 4];
        float4 w3 = *(const float4*)&W2[(kk * 4 + 3) * OUT_DIM + cg * 4];
        acc.x += f0.x * w0.x + f0.y * w1.x + f1.x * w2.x + f1.y * w3.x;
        acc.y += f0.x * w0.y + f0.y * w1.y + f1.x * w2.y + f1.y * w3.y;
        acc.z += f0.x * w0.z + f0.y * w1.z + f1.x * w2.z + f1.y * w3.z;
        acc.w += f0.x * w0.w + f0.y * w1.w + f1.x * w2.w + f1.y * w3.w;
    }
    float dv = dinv[row];
    union { __half2 h2v[2]; uint2 u; } pk;
    pk.h2v[0] = __floats2half2_rn(acc.x * dv, acc.y * dv);
    pk.h2v[1] = __floats2half2_rn(acc.z * dv, acc.w * dv);
    *(uint2*)&g2[(size_t)row * OUT_DIM + cg * 4] = pk.u;
}

// K6: layer-2 aggregation (pre-scaled fp16 in), fused bias + log_softmax.
__global__ __launch_bounds__(256) void k_agg_lsm(const int* __restrict__ rowptr,
        const unsigned short* __restrict__ esrc, const float* __restrict__ dinv,
        const uint2* __restrict__ g,        // [N][10] uint2 (=40 half)
        const float* __restrict__ b,
        float* __restrict__ out) {
    int wid  = (int)((blockIdx.x * (size_t)blockDim.x + threadIdx.x) >> 6);
    int lane = threadIdx.x & 63;
    if (wid >= N_NODES) return;
    int p = lane >> 4;
    int c = lane & 15;
    bool act = (c < 10);
    float ax = 0.f, ay = 0.f, az = 0.f, aw = 0.f;
#define ACC_U2(v)  do {                                            \
        float2 f0 = __half22float2(*(const __half2*)&(v).x);       \
        float2 f1 = __half22float2(*(const __half2*)&(v).y);       \
        ax += f0.x; ay += f0.y; az += f1.x; aw += f1.y; } while (0)
    if (p == 0 && act) { uint2 v = g[(size_t)wid * 10 + c]; ACC_U2(v); }
    int beg = rowptr[wid], deg = rowptr[wid + 1] - beg;
    for (int base = 0; base < deg; base += 64) {          // uniform
        int nb = deg - base; if (nb > 64) nb = 64;        // uniform
        int idx = (lane < nb) ? (int)esrc[beg + base + lane] : 0;
        for (int eb = 0; eb < nb; eb += 16) {             // uniform bound
            int e0 = eb + p;
            int s0 = __shfl(idx, e0);
            int s1 = __shfl(idx, e0 + 4);
            int s2 = __shfl(idx, e0 + 8);
            int s3 = __shfl(idx, e0 + 12);
            if (act) {
                if (e0 + 12 < nb) {
                    uint2 v0 = g[(size_t)s0 * 10 + c];
                    uint2 v1 = g[(size_t)s1 * 10 + c];
                    uint2 v2 = g[(size_t)s2 * 10 + c];
                    uint2 v3 = g[(size_t)s3 * 10 + c];
                    ACC_U2(v0); ACC_U2(v1); ACC_U2(v2); ACC_U2(v3);
                } else {
                    if (e0      < nb) { uint2 v = g[(size_t)s0 * 10 + c]; ACC_U2(v); }
                    if (e0 + 4  < nb) { uint2 v = g[(size_t)s1 * 10 + c]; ACC_U2(v); }
                    if (e0 + 8  < nb) { uint2 v = g[(size_t)s2 * 10 + c]; ACC_U2(v); }
                }
            }
        }
    }
#undef ACC_U2
    ax += __shfl_xor(ax, 16); ax += __shfl_xor(ax, 32);
    ay += __shfl_xor(ay, 16); ay += __shfl_xor(ay, 32);
    az += __shfl_xor(az, 16); az += __shfl_xor(az, 32);
    aw += __shfl_xor(aw, 16); aw += __shfl_xor(aw, 32);
    float dd = dinv[wid];
    float vx = -INFINITY, vy = -INFINITY, vz = -INFINITY, vw = -INFINITY;
    if (act) {
        float4 bb = *(const float4*)&b[c * 4];
        vx = ax * dd + bb.x; vy = ay * dd + bb.y;
        vz = az * dd + bb.z; vw = aw * dd + bb.w;
    }
    float m = fmaxf(fmaxf(vx, vy), fmaxf(vz, vw));
    for (int o = 8; o; o >>= 1) m = fmaxf(m, __shfl_xor(m, o));
    float es = act ? (__expf(vx - m) + __expf(vy - m) + __expf(vz - m) + __expf(vw - m)) : 0.f;
    for (int o = 8; o; o >>= 1) es += __shfl_xor(es, o);
    float ls = __logf(es);
    if (lane < 16 && act) {
        float4 o4 = make_float4(vx - m - ls, vy - m - ls, vz - m - ls, vw - m - ls);
        *(float4*)&out[(size_t)wid * OUT_DIM + c * 4] = o4;
    }
}

extern "C" void kernel_launch(void* const* d_in, const int* in_sizes, int n_in,
                              void* d_out, int out_size, void* d_ws, size_t ws_size,
                              hipStream_t stream) {
    const float* x    = (const float*)d_in[0];
    const int*   ei   = (const int*)d_in[1];
    const int*   srcp = ei;             // edge_index[0]
    const int*   dstp = ei + N_EDGES;   // edge_index[1]
    const float* W1   = (const float*)d_in[2];
    const float* b1   = (const float*)d_in[3];
    const float* W2   = (const float*)d_in[4];
    const float* b2   = (const float*)d_in[5];
    float* out = (float*)d_out;

    // workspace layout (~22.4 MB)
    char* p = (char*)d_ws;
    int*            cnt    = (int*)p;            p += (size_t)N_NODES * CNT_STRIDE * 4;
    int*            rowptr = (int*)p;            p += (size_t)(N_NODES + 4) * 4;
    unsigned short* rank_  = (unsigned short*)p; p += (size_t)N_EDGES * 2;
    unsigned short* esrc   = (unsigned short*)p; p += (size_t)N_EDGES * 2;
    int*            bsum   = (int*)p;            p += 256 * 4;
    float*          dinv   = (float*)p;          p += (size_t)N_NODES * 4;
    __half*         w1t    = (__half*)p;         p += (size_t)IN_DIM * HID_DIM * 2;
    __half*         g1     = (__half*)p;         p += (size_t)N_NODES * HID_DIM * 2;
    __half*         agg1   = (__half*)p;         p += (size_t)N_NODES * HID_DIM * 2;
    __half*         g2     = (__half*)p;         p += (size_t)N_NODES * OUT_DIM * 2;

    k_init<<<INIT_BLOCKS, 256, 0, stream>>>(cnt, W1, w1t);

    k_gemm1_count<<<GEMM1_BLOCKS + CNT_BLOCKS, 256, 0, stream>>>(
        x, w1t, g1, dstp, cnt, rank_);

    k_scan1<<<NBLK, 256, 0, stream>>>(cnt, rowptr, bsum);
    k_scan23<<<NBLK, 256, 0, stream>>>(rowptr, bsum, cnt, dinv);

    k_fill_scale<<<FILL_BLOCKS + SCALE_BLOCKS, 256, 0, stream>>>(
        srcp, dstp, rowptr, rank_, esrc, g1, dinv);

    k_agg_relu<<<(N_NODES + 3) / 4, 256, 0, stream>>>(rowptr, esrc, dinv,
                                                      (const uint4*)g1, b1, agg1);

    k_gemm2<<<(N_NODES * (OUT_DIM / 4) + 255) / 256, 256, 0, stream>>>(agg1, W2, dinv, g2);

    k_agg_lsm<<<(N_NODES + 3) / 4, 256, 0, stream>>>(rowptr, esrc, dinv,
                                                     (const uint2*)g2, b2, out);
}